// Round 1
// baseline (80.531 us; speedup 1.0000x reference)
//
#include <hip/hip_runtime.h>

// Chamfer distance, B=4, N=M=8192, D=3, fp32.
// R12: hoist payload conversion into a one-shot prep kernel; mega is now
// LDS-free and streams MFMA A/B fragments directly from precomputed global
// payload arrays (coalesced 1KB dwordx4 loads, L2-resident). Removes the
// 16x-redundant target staging, 8x-redundant query packing, LDS barriers,
// and shrinks acc to WNT=2 (est ~110 VGPR -> 4 waves/SIMD, 2048 blocks).
// Distance math, part layout, and reduce kernel are bit-identical to R11
// (absmax 0.0 preserved). Payload k0..15, query x target:
//   -2h.h | -2l.h | -2h.l | qn.1 | 1.tn | 0
//   query vec:  [ax,ay,az, cx,cy,cz, ax,ay,az, qn1,qn2,qn3, 1,1,1, 0]
//   target vec: [hx,hy,hz, hx,hy,hz, lx,ly,lz, 1,1,1, tn1,tn2,tn3, 0]

typedef __attribute__((ext_vector_type(8)))  short short8;
typedef __attribute__((ext_vector_type(16))) float f32x16;

#define BATCH 4
#define NPTS 8192
#define TOTALQ (BATCH * NPTS)   // 32768
#define BLK 256
#define WNT 2                   // 32-col B tiles per wave -> 64 queries/wave
#define BCOLS (4 * WNT * 32)    // 256 query cols per block (4 waves)
#define NCHUNK (TOTALQ / BCOLS) // 128
#define MSPLIT 8                // target slices per batch
#define MC (NPTS / MSPLIT)      // 1024 targets per block
#define MT_PER (MC / 32)        // 32 target tiles

// ws layout (uint4 units of 16 B): A = target-role payload, B = query-role.
#define PAY_APRED 0
#define PAY_ATARG (2 * TOTALQ)           // 65536
#define PAY_BPRED (4 * TOTALQ)           // 131072
#define PAY_BTARG (6 * TOTALQ)           // 196608
#define PART_OFF_BYTES ((size_t)(8 * TOTALQ) * 16)   // 4 MB

__device__ __forceinline__ unsigned short f2bf(float f) {  // RTN-even
    unsigned int u = __float_as_uint(f);
    u += 0x7FFFu + ((u >> 16) & 1u);
    return (unsigned short)(u >> 16);
}
__device__ __forceinline__ float bf2f(unsigned short h) {
    return __uint_as_float(((unsigned int)h) << 16);
}
__device__ __forceinline__ unsigned int pk2(unsigned short a, unsigned short b) {
    return (unsigned int)a | ((unsigned int)b << 16);
}

struct Payload {
    unsigned short hx, hy, hz, lx, ly, lz, n1, n2, n3;
};
__device__ __forceinline__ Payload split_point(float x, float y, float z) {
    Payload P;
    P.hx = f2bf(x);  P.hy = f2bf(y);  P.hz = f2bf(z);
    P.lx = f2bf(x - bf2f(P.hx));
    P.ly = f2bf(y - bf2f(P.hy));
    P.lz = f2bf(z - bf2f(P.hz));
    float nrm = fmaf(z, z, fmaf(y, y, x * x));
    P.n1 = f2bf(nrm);
    float r1 = nrm - bf2f(P.n1);
    P.n2 = f2bf(r1);
    P.n3 = f2bf(r1 - bf2f(P.n2));
    return P;
}

// ---- one-shot payload conversion: 65536 points -> A-role + B-role ----
__global__ __launch_bounds__(BLK) void chamfer_prep_kernel(
        const float* __restrict__ pred, const float* __restrict__ target,
        uint4* __restrict__ pay, float* __restrict__ out)
{
    int t = blockIdx.x * BLK + threadIdx.x;   // 0..65535
    if (t == 0) out[0] = 0.0f;                // consumed by reduce kernel
    int which = t >> 15;                      // 0 = pred, 1 = target
    int i = t & (TOTALQ - 1);
    const float* __restrict__ src = which ? target : pred;
    float x = src[3 * i], y = src[3 * i + 1], z = src[3 * i + 2];
    Payload P = split_point(x, y, z);
    const unsigned short ONE = 0x3F80;

    // A-role (min-over operand, rows of the MFMA)
    int abase = (which ? PAY_ATARG : PAY_APRED) + 2 * i;
    pay[abase]     = (uint4){ pk2(P.hx, P.hy), pk2(P.hz, P.hx),
                              pk2(P.hy, P.hz), pk2(P.lx, P.ly) };
    pay[abase + 1] = (uint4){ pk2(P.lz, ONE), pk2(ONE, ONE),
                              pk2(P.n1, P.n2), pk2(P.n3, 0) };

    // B-role (query operand, cols of the MFMA)
    unsigned short ax = f2bf(-2.f * bf2f(P.hx)),
                   ay = f2bf(-2.f * bf2f(P.hy)),
                   az = f2bf(-2.f * bf2f(P.hz));
    unsigned short cx = f2bf(-2.f * bf2f(P.lx)),
                   cy = f2bf(-2.f * bf2f(P.ly)),
                   cz = f2bf(-2.f * bf2f(P.lz));
    int bbase = (which ? PAY_BTARG : PAY_BPRED) + 2 * i;
    pay[bbase]     = (uint4){ pk2(ax, ay), pk2(az, cx), pk2(cy, cz), pk2(ax, ay) };
    pay[bbase + 1] = (uint4){ pk2(az, P.n1), pk2(P.n2, P.n3),
                              pk2(ONE, ONE), pk2(ONE, 0) };
}

// ---- main pairwise-min kernel: LDS-free, streams fragments from global ----
__global__ __launch_bounds__(BLK) void chamfer_mega_kernel(
        const uint4* __restrict__ pay, float* __restrict__ part)
{
    const int dir = blockIdx.z;
    const int nch = blockIdx.x;            // 0..127 (256-query-col chunk)
    const int b   = nch >> 5;              // batch (32 chunks per batch)
    const int ms  = blockIdx.y;            // 0..7 target slice
    const int w    = threadIdx.x >> 6;
    const int lane = threadIdx.x & 63;
    const int c = lane & 31;               // row (A) / col (B) within tile
    const int g = lane >> 5;               // k-half

    // dir=0: queries=pred (B), min-over=target (A). dir=1: swapped.
    const uint4* __restrict__ Ap = pay + (dir ? PAY_APRED : PAY_ATARG)
                                 + (size_t)(b * NPTS + ms * MC) * 2;
    const uint4* __restrict__ Bq = pay + (dir ? PAY_BTARG : PAY_BPRED);

    // B fragments: coalesced (lane L covers byte 32c+16g of a 2KB span)
    const int colstart = nch * BCOLS + w * (WNT * 32);
    short8 bq[WNT];
    #pragma unroll
    for (int nt = 0; nt < WNT; ++nt) {
        uint4 v = Bq[2 * (colstart + nt * 32 + c) + g];
        bq[nt] = *(short8*)&v;
    }

    f32x16 acc[WNT];
    #pragma unroll
    for (int nt = 0; nt < WNT; ++nt)
        #pragma unroll
        for (int r = 0; r < 16; ++r) acc[nt][r] = 3.4e38f;

    f32x16 vzero;
    #pragma unroll
    for (int r = 0; r < 16; ++r) vzero[r] = 0.0f;

    // ---- main loop: 2 global dwordx4 (A tiles) + 4 MFMA + 32 min3 ----
    #pragma unroll 4
    for (int mt = 0; mt < MT_PER; mt += 2) {
        uint4 va0 = Ap[(mt * 32 + c) * 2 + g];
        uint4 va1 = Ap[((mt + 1) * 32 + c) * 2 + g];
        short8 at0 = *(short8*)&va0;
        short8 at1 = *(short8*)&va1;
        #pragma unroll
        for (int nt = 0; nt < WNT; ++nt) {
            f32x16 d0, d1;
            // A = target tile, B = query tile (regs); VGPR dst.
            // s_nop pads the MFMA-write -> VALU-read hazard (asm is opaque
            // to the hazard recognizer).
            asm("v_mfma_f32_32x32x16_bf16 %0, %2, %4, %5\n\t"
                "v_mfma_f32_32x32x16_bf16 %1, %3, %4, %5\n\t"
                "s_nop 7\n\t"
                "s_nop 7"
                : "=&v"(d0), "=&v"(d1)
                : "v"(at0), "v"(at1), "v"(bq[nt]), "v"(vzero));
            #pragma unroll
            for (int r = 0; r < 16; ++r)
                acc[nt][r] = fminf(fminf(acc[nt][r], d0[r]), d1[r]); // v_min3
        }
    }

    // ---- epilogue: min over the 16 regs (rows) in-lane + 1 shfl for g ----
    float* rp = part + (size_t)(dir * MSPLIT + ms) * TOTALQ;
    #pragma unroll
    for (int nt = 0; nt < WNT; ++nt) {
        f32x16 v = acc[nt];
        float m0 = fminf(fminf(v[0],  v[1]),  fminf(v[2],  v[3]));
        float m1 = fminf(fminf(v[4],  v[5]),  fminf(v[6],  v[7]));
        float m2 = fminf(fminf(v[8],  v[9]),  fminf(v[10], v[11]));
        float m3 = fminf(fminf(v[12], v[13]), fminf(v[14], v[15]));
        float m  = fminf(fminf(m0, m1), fminf(m2, m3));
        m = fminf(m, __shfl_xor(m, 32, 64));    // fold the two k-half rows
        if (g == 0) rp[colstart + nt * 32 + c] = m;
    }
}

__global__ __launch_bounds__(BLK) void chamfer_reduce_kernel(
        const float* __restrict__ part, float* __restrict__ out)
{
    int gl = blockIdx.x * BLK + threadIdx.x;   // 0..65535
    int dir = gl >> 15, i = gl & (TOTALQ - 1);

    const float* p = part + (size_t)dir * MSPLIT * TOTALQ + i;
    float m = p[0];
    #pragma unroll
    for (int s = 1; s < MSPLIT; ++s)
        m = fminf(m, p[(size_t)s * TOTALQ]);

    float acc = m * (1.0f / (float)TOTALQ);
    #pragma unroll
    for (int off = 32; off > 0; off >>= 1)
        acc += __shfl_down(acc, off, 64);
    __shared__ float wsum[BLK / 64];
    int lane = threadIdx.x & 63, wid = threadIdx.x >> 6;
    if (lane == 0) wsum[wid] = acc;
    __syncthreads();
    if (threadIdx.x == 0) {
        float s = 0.0f;
        #pragma unroll
        for (int wv = 0; wv < BLK / 64; ++wv) s += wsum[wv];
        atomicAdd(out, s);
    }
}

extern "C" void kernel_launch(void* const* d_in, const int* in_sizes, int n_in,
                              void* d_out, int out_size, void* d_ws, size_t ws_size,
                              hipStream_t stream) {
    const float* pred   = (const float*)d_in[0];
    const float* target = (const float*)d_in[1];
    float*       out    = (float*)d_out;
    uint4*       pay    = (uint4*)d_ws;                          // 4 MB payloads
    float*       part   = (float*)((char*)d_ws + PART_OFF_BYTES); // 2 MB partials

    hipLaunchKernelGGL(chamfer_prep_kernel, dim3(2 * TOTALQ / BLK), dim3(BLK),
                       0, stream, pred, target, pay, out);

    dim3 grid(NCHUNK, MSPLIT, 2);   // 128 x 8 x 2 = 2048 blocks
    hipLaunchKernelGGL(chamfer_mega_kernel, grid, dim3(BLK), 0, stream,
                       pay, part);

    hipLaunchKernelGGL(chamfer_reduce_kernel, dim3(2 * TOTALQ / BLK), dim3(BLK),
                       0, stream, (const float*)part, out);
}

// Round 2
// 78.277 us; speedup vs baseline: 1.0288x; 1.0288x over previous
//
#include <hip/hip_runtime.h>

// Chamfer distance, B=4, N=M=8192, D=3, fp32.
// R13: revert R12's prep-kernel split (launch overhead ~3us > its value;
// measured +3.7us total). Back to R11's two-kernel LDS-staged structure,
// rebalanced for occupancy: WNT=2 (acc 32 regs instead of 64), BCOLS=256,
// grid 2048 uniform blocks (8 blocks/CU over 2 clean rounds), and
// __launch_bounds__(256,4) to pin VGPR<=128 -> 4 waves/SIMD so the
// MFMA->min3 s_nop window and ds_read latency hide under co-resident waves.
// Payload math, fold order, part layout identical to R11 (absmax 0.0).
//   -2h.h | -2l.h | -2h.l | qn.1 | 1.tn | 0
//   query vec:  [ax,ay,az, cx,cy,cz, ax,ay,az, qn1,qn2,qn3, 1,1,1, 0]
//   target vec: [hx,hy,hz, hx,hy,hz, lx,ly,lz, 1,1,1, tn1,tn2,tn3, 0]

typedef __attribute__((ext_vector_type(8)))  short short8;
typedef __attribute__((ext_vector_type(16))) float f32x16;

#define BATCH 4
#define NPTS 8192
#define TOTALQ (BATCH * NPTS)   // 32768
#define BLK 256
#define WNT 2                   // 32-col B tiles per wave -> 64 queries/wave
#define BCOLS (4 * WNT * 32)    // 256 query cols per block (4 waves)
#define NCHUNK (TOTALQ / BCOLS) // 128 (32 chunks per batch)
#define MSPLIT 8                // target slices per batch
#define MC (NPTS / MSPLIT)      // 1024 targets per block, single LDS stage
#define MT_PER (MC / 32)        // 32 target tiles

__device__ __forceinline__ unsigned short f2bf(float f) {  // RTN-even
    unsigned int u = __float_as_uint(f);
    u += 0x7FFFu + ((u >> 16) & 1u);
    return (unsigned short)(u >> 16);
}
__device__ __forceinline__ float bf2f(unsigned short h) {
    return __uint_as_float(((unsigned int)h) << 16);
}
__device__ __forceinline__ unsigned int pk2(unsigned short a, unsigned short b) {
    return (unsigned int)a | ((unsigned int)b << 16);
}

struct Payload {
    unsigned short hx, hy, hz, lx, ly, lz, n1, n2, n3;
};
__device__ __forceinline__ Payload split_point(float x, float y, float z) {
    Payload P;
    P.hx = f2bf(x);  P.hy = f2bf(y);  P.hz = f2bf(z);
    P.lx = f2bf(x - bf2f(P.hx));
    P.ly = f2bf(y - bf2f(P.hy));
    P.lz = f2bf(z - bf2f(P.hz));
    float nrm = fmaf(z, z, fmaf(y, y, x * x));
    P.n1 = f2bf(nrm);
    float r1 = nrm - bf2f(P.n1);
    P.n2 = f2bf(r1);
    P.n3 = f2bf(r1 - bf2f(P.n2));
    return P;
}

__global__ __launch_bounds__(BLK, 4) void chamfer_mega_kernel(
        const float* __restrict__ pred, const float* __restrict__ target,
        float* __restrict__ part, float* __restrict__ out)
{
    const int dir = blockIdx.z;
    const float* __restrict__ Q  = dir ? target : pred;   // outputs (B cols)
    const float* __restrict__ Tg = dir ? pred : target;   // min-over (A rows, LDS)

    const int nch = blockIdx.x;            // 0..127 (256-query-col chunk)
    const int b   = nch >> 5;              // batch (32 chunks per batch)
    const int ms  = blockIdx.y;            // 0..7 target slice
    const int w    = threadIdx.x >> 6;
    const int lane = threadIdx.x & 63;
    const int c = lane & 31;               // row (A) / col (B) within tile
    const int g = lane >> 5;               // k-half
    const unsigned short ONE = 0x3F80;

    if (blockIdx.x == 0 && blockIdx.y == 0 && blockIdx.z == 0 &&
        threadIdx.x == 0) out[0] = 0.0f;   // consumed after kernel boundary

    __shared__ uint4 ldsb[2][MC];          // 32 KB (two k-halves)

    // ---- stage MC target points: raw read -> payload -> LDS (A operand) ----
    #pragma unroll
    for (int j = 0; j < MC / BLK; ++j) {
        int p = j * BLK + threadIdx.x;
        size_t gp = (size_t)b * NPTS + (size_t)ms * MC + p;
        float x = Tg[3 * gp], y = Tg[3 * gp + 1], z = Tg[3 * gp + 2];
        Payload P = split_point(x, y, z);
        ldsb[0][p] = (uint4){ pk2(P.hx, P.hy), pk2(P.hz, P.hx),
                              pk2(P.hy, P.hz), pk2(P.lx, P.ly) };
        ldsb[1][p] = (uint4){ pk2(P.lz, ONE), pk2(ONE, ONE),
                              pk2(P.n1, P.n2), pk2(P.n3, 0) };
    }

    // ---- B fragments (queries): in-register pack, col = colstart + nt*32 + c ----
    const int colstart = nch * BCOLS + w * (WNT * 32);
    short8 bq[WNT];
    #pragma unroll
    for (int nt = 0; nt < WNT; ++nt) {
        int r = colstart + nt * 32 + c;
        float x = Q[3 * r], y = Q[3 * r + 1], z = Q[3 * r + 2];
        Payload P = split_point(x, y, z);
        unsigned short ax = f2bf(-2.f * bf2f(P.hx)),
                       ay = f2bf(-2.f * bf2f(P.hy)),
                       az = f2bf(-2.f * bf2f(P.hz));
        unsigned short cx = f2bf(-2.f * bf2f(P.lx)),
                       cy = f2bf(-2.f * bf2f(P.ly)),
                       cz = f2bf(-2.f * bf2f(P.lz));
        uint4 h0 = { pk2(ax, ay), pk2(az, cx), pk2(cy, cz), pk2(ax, ay) };
        uint4 h1 = { pk2(az, P.n1), pk2(P.n2, P.n3), pk2(ONE, ONE), pk2(ONE, 0) };
        uint4 sel = g ? h1 : h0;
        bq[nt] = *(short8*)&sel;
    }

    f32x16 acc[WNT];
    #pragma unroll
    for (int nt = 0; nt < WNT; ++nt)
        #pragma unroll
        for (int r = 0; r < 16; ++r) acc[nt][r] = 3.4e38f;

    f32x16 vzero;
    #pragma unroll
    for (int r = 0; r < 16; ++r) vzero[r] = 0.0f;

    __syncthreads();

    const ushort* ldsu = (const ushort*)&ldsb[g][0];   // this lane's k-half

    // ---- main loop: 2 ds_read_b128 (A target tiles) + 4 MFMA + 32 min3 ----
    #pragma unroll 4
    for (int mt = 0; mt < MT_PER; mt += 2) {
        short8 at0 = *(const short8*)(ldsu + (mt * 32 + c) * 8);
        short8 at1 = *(const short8*)(ldsu + ((mt + 1) * 32 + c) * 8);
        #pragma unroll
        for (int nt = 0; nt < WNT; ++nt) {
            f32x16 d0, d1;
            // A = target tile (LDS), B = query tile (regs); VGPR dst.
            // s_nop pads the MFMA-write -> VALU-read hazard (asm is opaque
            // to the hazard recognizer).
            asm("v_mfma_f32_32x32x16_bf16 %0, %2, %4, %5\n\t"
                "v_mfma_f32_32x32x16_bf16 %1, %3, %4, %5\n\t"
                "s_nop 7\n\t"
                "s_nop 7"
                : "=&v"(d0), "=&v"(d1)
                : "v"(at0), "v"(at1), "v"(bq[nt]), "v"(vzero));
            #pragma unroll
            for (int r = 0; r < 16; ++r)
                acc[nt][r] = fminf(fminf(acc[nt][r], d0[r]), d1[r]); // v_min3
        }
    }

    // ---- epilogue: min over the 16 regs (rows) in-lane + 1 shfl for g ----
    float* rp = part + (size_t)(dir * MSPLIT + ms) * TOTALQ;
    #pragma unroll
    for (int nt = 0; nt < WNT; ++nt) {
        f32x16 v = acc[nt];
        float m0 = fminf(fminf(v[0],  v[1]),  fminf(v[2],  v[3]));
        float m1 = fminf(fminf(v[4],  v[5]),  fminf(v[6],  v[7]));
        float m2 = fminf(fminf(v[8],  v[9]),  fminf(v[10], v[11]));
        float m3 = fminf(fminf(v[12], v[13]), fminf(v[14], v[15]));
        float m  = fminf(fminf(m0, m1), fminf(m2, m3));
        m = fminf(m, __shfl_xor(m, 32, 64));    // fold the two k-half rows
        if (g == 0) rp[colstart + nt * 32 + c] = m;
    }
}

__global__ __launch_bounds__(BLK) void chamfer_reduce_kernel(
        const float* __restrict__ part, float* __restrict__ out)
{
    int gl = blockIdx.x * BLK + threadIdx.x;   // 0..65535
    int dir = gl >> 15, i = gl & (TOTALQ - 1);

    const float* p = part + (size_t)dir * MSPLIT * TOTALQ + i;
    float m = p[0];
    #pragma unroll
    for (int s = 1; s < MSPLIT; ++s)
        m = fminf(m, p[(size_t)s * TOTALQ]);

    float acc = m * (1.0f / (float)TOTALQ);
    #pragma unroll
    for (int off = 32; off > 0; off >>= 1)
        acc += __shfl_down(acc, off, 64);
    __shared__ float wsum[BLK / 64];
    int lane = threadIdx.x & 63, wid = threadIdx.x >> 6;
    if (lane == 0) wsum[wid] = acc;
    __syncthreads();
    if (threadIdx.x == 0) {
        float s = 0.0f;
        #pragma unroll
        for (int wv = 0; wv < BLK / 64; ++wv) s += wsum[wv];
        atomicAdd(out, s);
    }
}

extern "C" void kernel_launch(void* const* d_in, const int* in_sizes, int n_in,
                              void* d_out, int out_size, void* d_ws, size_t ws_size,
                              hipStream_t stream) {
    const float* pred   = (const float*)d_in[0];
    const float* target = (const float*)d_in[1];
    float*       out    = (float*)d_out;
    float*       part   = (float*)d_ws;   // 2 dirs x 8 slices x 32768 = 2 MB

    dim3 grid(NCHUNK, MSPLIT, 2);   // 128 x 8 x 2 = 2048 blocks
    hipLaunchKernelGGL(chamfer_mega_kernel, grid, dim3(BLK), 0, stream,
                       pred, target, part, out);

    hipLaunchKernelGGL(chamfer_reduce_kernel, dim3(2 * TOTALQ / BLK), dim3(BLK),
                       0, stream, (const float*)part, out);
}